// Round 1
// baseline (1565.138 us; speedup 1.0000x reference)
//
#include <hip/hip_runtime.h>

#define N_NODES 50000
#define N_EDGES 800000
#define F_IN 128
#define DIM 256
#define N_GRAPHS 512
#define BN_EPS 1e-5f

// ---------------- CSR build ----------------

__global__ void count_deg(const int* __restrict__ dst, int* __restrict__ deg, int nE) {
    int e = blockIdx.x * 256 + threadIdx.x;
    if (e < nE) atomicAdd(&deg[dst[e]], 1);
}

__global__ void scan_deg(const int* __restrict__ deg, int* __restrict__ row_start, int n) {
    __shared__ int buf[1024];
    __shared__ int carry;
    if (threadIdx.x == 0) { carry = 0; row_start[0] = 0; }
    __syncthreads();
    for (int base = 0; base < n; base += 1024) {
        int i = base + (int)threadIdx.x;
        int v = (i < n) ? deg[i] : 0;
        buf[threadIdx.x] = v;
        __syncthreads();
        for (int off = 1; off < 1024; off <<= 1) {
            int t = (threadIdx.x >= (unsigned)off) ? buf[threadIdx.x - off] : 0;
            __syncthreads();
            buf[threadIdx.x] += t;
            __syncthreads();
        }
        int incl = buf[threadIdx.x] + carry;
        if (i < n) row_start[i + 1] = incl;
        __syncthreads();
        if (threadIdx.x == 1023) carry = incl;
        __syncthreads();
    }
}

__global__ void fill_csr(const int* __restrict__ src, const int* __restrict__ dst,
                         int* __restrict__ cursor, int* __restrict__ srcs, int nE) {
    int e = blockIdx.x * 256 + threadIdx.x;
    if (e < nE) {
        int p = atomicAdd(&cursor[dst[e]], 1);
        srcs[p] = src[e];
    }
}

__global__ void graph_bounds(const int* __restrict__ batch, int* __restrict__ gstart,
                             int n, int ngraphs) {
    int g = blockIdx.x * 256 + threadIdx.x;
    if (g > ngraphs) return;
    int lo = 0, hi = n;
    while (lo < hi) {
        int mid = (lo + hi) >> 1;
        if (batch[mid] < g) lo = mid + 1; else hi = mid;
    }
    gstart[g] = lo;
}

// ---------------- aggregation: agg = h + sum_{j->i} h_j ----------------
// one wave per node; lane*4 = feature column; gather rows are coalesced 1KB bursts

__global__ void aggregate(const float* __restrict__ h, int stride, int F,
                          const int* __restrict__ row_start, const int* __restrict__ srcs,
                          float* __restrict__ outp, int n) {
    int node = (int)(((size_t)blockIdx.x * blockDim.x + threadIdx.x) >> 6);
    int lane = threadIdx.x & 63;
    if (node >= n) return;
    int c = lane << 2;
    if (c >= F) return;
    float4 acc = *(const float4*)(h + (size_t)node * stride + c);
    int s = row_start[node], e = row_start[node + 1];
    int j = s;
    for (; j + 3 < e; j += 4) {
        int s0 = srcs[j], s1 = srcs[j + 1], s2 = srcs[j + 2], s3 = srcs[j + 3];
        float4 v0 = *(const float4*)(h + (size_t)s0 * stride + c);
        float4 v1 = *(const float4*)(h + (size_t)s1 * stride + c);
        float4 v2 = *(const float4*)(h + (size_t)s2 * stride + c);
        float4 v3 = *(const float4*)(h + (size_t)s3 * stride + c);
        acc.x += (v0.x + v1.x) + (v2.x + v3.x);
        acc.y += (v0.y + v1.y) + (v2.y + v3.y);
        acc.z += (v0.z + v1.z) + (v2.z + v3.z);
        acc.w += (v0.w + v1.w) + (v2.w + v3.w);
    }
    for (; j < e; ++j) {
        int s0 = srcs[j];
        float4 v = *(const float4*)(h + (size_t)s0 * stride + c);
        acc.x += v.x; acc.y += v.y; acc.z += v.z; acc.w += v.w;
    }
    *(float4*)(outp + (size_t)node * F + c) = acc;
}

// ---------------- fp32 tiled GEMM: C = relu(A @ W + bias), W: K x 256 ----------------
// 64x64 tile per block, 256 threads, 4x4 micro-tile per thread

__global__ __launch_bounds__(256) void gemm_bias_relu(
    const float* __restrict__ A, const float* __restrict__ W,
    const float* __restrict__ bias, float* __restrict__ C, int M, int K) {
    __shared__ float As[16][68];  // [k][m], stride 68 keeps 16B-aligned rows, <=2-way banks
    __shared__ float Bs[16][64];  // [k][n]
    const int bm = blockIdx.x * 64;
    const int bn = blockIdx.y * 64;
    const int tid = threadIdx.x;
    const int tn = tid & 15, tm = tid >> 4;
    float acc[4][4] = {{0.f}};
    for (int k0 = 0; k0 < K; k0 += 16) {
        int r = tid >> 2, kc = (tid & 3) << 2;
        float4 av = make_float4(0.f, 0.f, 0.f, 0.f);
        int row = bm + r;
        if (row < M) av = *(const float4*)(A + (size_t)row * K + k0 + kc);
        int kr = tid >> 4, nc = (tid & 15) << 2;
        float4 bv = *(const float4*)(W + (size_t)(k0 + kr) * 256 + bn + nc);
        As[kc + 0][r] = av.x; As[kc + 1][r] = av.y;
        As[kc + 2][r] = av.z; As[kc + 3][r] = av.w;
        *(float4*)&Bs[kr][nc] = bv;
        __syncthreads();
#pragma unroll
        for (int k = 0; k < 16; ++k) {
            float4 a = *(const float4*)&As[k][tm << 2];
            float4 b = *(const float4*)&Bs[k][tn << 2];
            acc[0][0] += a.x * b.x; acc[0][1] += a.x * b.y; acc[0][2] += a.x * b.z; acc[0][3] += a.x * b.w;
            acc[1][0] += a.y * b.x; acc[1][1] += a.y * b.y; acc[1][2] += a.y * b.z; acc[1][3] += a.y * b.w;
            acc[2][0] += a.z * b.x; acc[2][1] += a.z * b.y; acc[2][2] += a.z * b.z; acc[2][3] += a.z * b.w;
            acc[3][0] += a.w * b.x; acc[3][1] += a.w * b.y; acc[3][2] += a.w * b.z; acc[3][3] += a.w * b.w;
        }
        __syncthreads();
    }
    int col = bn + (tn << 2);
    float4 bia = *(const float4*)(bias + col);
#pragma unroll
    for (int i = 0; i < 4; ++i) {
        int row = bm + (tm << 2) + i;
        if (row < M) {
            float4 o;
            o.x = fmaxf(acc[i][0] + bia.x, 0.f);
            o.y = fmaxf(acc[i][1] + bia.y, 0.f);
            o.z = fmaxf(acc[i][2] + bia.z, 0.f);
            o.w = fmaxf(acc[i][3] + bia.w, 0.f);
            *(float4*)(C + (size_t)row * 256 + col) = o;
        }
    }
}

// ---------------- batchnorm ----------------

__global__ void bn_stats(const float* __restrict__ m, float* __restrict__ sums, int n) {
    int col = threadIdx.x;  // 256 threads
    float s = 0.f, s2 = 0.f;
    for (int r = blockIdx.x; r < n; r += gridDim.x) {
        float v = m[(size_t)r * 256 + col];
        s += v; s2 += v * v;
    }
    atomicAdd(&sums[col], s);
    atomicAdd(&sums[256 + col], s2);
}

__global__ void bn_finalize(const float* __restrict__ sums, const float* __restrict__ g,
                            const float* __restrict__ b, float* __restrict__ ss, float inv_n) {
    int c = threadIdx.x;
    float mu = sums[c] * inv_n;
    float var = sums[256 + c] * inv_n - mu * mu;
    float sc = g[c] / sqrtf(var + BN_EPS);
    ss[c] = sc;
    ss[256 + c] = b[c] - mu * sc;
}

__global__ void bn_apply(const float* __restrict__ m, const float* __restrict__ ss,
                         float* __restrict__ out_nodes, int n, int col_off) {
    size_t idx = (size_t)blockIdx.x * blockDim.x + threadIdx.x;  // over n*64 float4s
    if (idx >= (size_t)n * 64) return;
    int row = (int)(idx >> 6);
    int c4 = (int)(idx & 63) << 2;
    float4 v = *(const float4*)(m + (size_t)row * 256 + c4);
    float4 sc = *(const float4*)(ss + c4);
    float4 sh = *(const float4*)(ss + 256 + c4);
    float4 o;
    o.x = v.x * sc.x + sh.x;
    o.y = v.y * sc.y + sh.y;
    o.z = v.z * sc.z + sh.z;
    o.w = v.w * sc.w + sh.w;
    *(float4*)(out_nodes + (size_t)row * 768 + col_off + c4) = o;
}

// ---------------- per-graph add pool (batch is sorted) ----------------

__global__ void pool_graphs(const float* __restrict__ out_nodes, const int* __restrict__ gstart,
                            float* __restrict__ pooled) {
    int g = blockIdx.x;       // 512
    int c = threadIdx.x;      // 256
    float a0 = 0.f, a1 = 0.f, a2 = 0.f;
    int s = gstart[g], e = gstart[g + 1];
    for (int i = s; i < e; ++i) {
        const float* r = out_nodes + (size_t)i * 768;
        a0 += r[c]; a1 += r[c + 256]; a2 += r[c + 512];
    }
    pooled[(size_t)g * 768 + c] = a0;
    pooled[(size_t)g * 768 + c + 256] = a1;
    pooled[(size_t)g * 768 + c + 512] = a2;
}

// ---------------- launch ----------------

extern "C" void kernel_launch(void* const* d_in, const int* in_sizes, int n_in,
                              void* d_out, int out_size, void* d_ws, size_t ws_size,
                              hipStream_t stream) {
    const float* x = (const float*)d_in[0];
    const int* esrc = (const int*)d_in[1];
    const int* edst = esrc + N_EDGES;
    const int* batch = (const int*)d_in[2];

    const float* w1[3] = {(const float*)d_in[3], (const float*)d_in[9],  (const float*)d_in[15]};
    const float* b1[3] = {(const float*)d_in[4], (const float*)d_in[10], (const float*)d_in[16]};
    const float* w2[3] = {(const float*)d_in[5], (const float*)d_in[11], (const float*)d_in[17]};
    const float* b2[3] = {(const float*)d_in[6], (const float*)d_in[12], (const float*)d_in[18]};
    const float* bng[3] = {(const float*)d_in[7], (const float*)d_in[13], (const float*)d_in[19]};
    const float* bnb[3] = {(const float*)d_in[8], (const float*)d_in[14], (const float*)d_in[20]};

    float* out_pooled = (float*)d_out;
    float* out_nodes = (float*)d_out + (size_t)N_GRAPHS * 768;

    float* A = (float*)d_ws;                       // N_NODES*256
    float* T = A + (size_t)N_NODES * 256;          // N_NODES*256
    float* sums = T + (size_t)N_NODES * 256;       // 512
    float* ss = sums + 512;                        // 512
    int* deg = (int*)(ss + 512);                   // N_NODES
    int* row_start = deg + N_NODES;                // N_NODES+1
    int* cursor = row_start + N_NODES + 2;         // N_NODES
    int* srcs = cursor + N_NODES;                  // N_EDGES
    int* gstart = srcs + N_EDGES;                  // N_GRAPHS+1

    // CSR build (once; reused by all 3 layers)
    hipMemsetAsync(deg, 0, N_NODES * sizeof(int), stream);
    count_deg<<<(N_EDGES + 255) / 256, 256, 0, stream>>>(edst, deg, N_EDGES);
    scan_deg<<<1, 1024, 0, stream>>>(deg, row_start, N_NODES);
    hipMemcpyAsync(cursor, row_start, N_NODES * sizeof(int), hipMemcpyDeviceToDevice, stream);
    fill_csr<<<(N_EDGES + 255) / 256, 256, 0, stream>>>(esrc, edst, cursor, srcs, N_EDGES);
    graph_bounds<<<3, 256, 0, stream>>>(batch, gstart, N_NODES, N_GRAPHS);

    const float* hin = x;
    int hstride = F_IN, F = F_IN;
    for (int L = 0; L < 3; ++L) {
        aggregate<<<(N_NODES + 3) / 4, 256, 0, stream>>>(hin, hstride, F, row_start, srcs, A, N_NODES);
        gemm_bias_relu<<<dim3((N_NODES + 63) / 64, 4), 256, 0, stream>>>(A, w1[L], b1[L], T, N_NODES, F);
        gemm_bias_relu<<<dim3((N_NODES + 63) / 64, 4), 256, 0, stream>>>(T, w2[L], b2[L], A, N_NODES, DIM);
        hipMemsetAsync(sums, 0, 512 * sizeof(float), stream);
        bn_stats<<<256, 256, 0, stream>>>(A, sums, N_NODES);
        bn_finalize<<<1, 256, 0, stream>>>(sums, bng[L], bnb[L], ss, 1.0f / N_NODES);
        bn_apply<<<(N_NODES * 64 + 255) / 256, 256, 0, stream>>>(A, ss, out_nodes, N_NODES, L * 256);
        hin = out_nodes + L * 256;
        hstride = 768;
        F = DIM;
    }
    pool_graphs<<<N_GRAPHS, 256, 0, stream>>>(out_nodes, gstart, out_pooled);
}

// Round 2
// 829.594 us; speedup vs baseline: 1.8866x; 1.8866x over previous
//
#include <hip/hip_runtime.h>

#define N_NODES 50000
#define N_EDGES 800000
#define F_IN 128
#define DIM 256
#define N_GRAPHS 512
#define BN_EPS 1e-5f

typedef unsigned short u16;
typedef unsigned int u32;
using floatx4 = __attribute__((ext_vector_type(4))) float;
using short8 = __attribute__((ext_vector_type(8))) short;

__device__ __forceinline__ u16 f2b(float f) {
    u32 u = __float_as_uint(f);
    return (u16)((u + 0x7fffu + ((u >> 16) & 1u)) >> 16);
}
__device__ __forceinline__ float blo(u32 u) { return __uint_as_float(u << 16); }
__device__ __forceinline__ float bhi(u32 u) { return __uint_as_float(u & 0xffff0000u); }
__device__ __forceinline__ u32 pack2(float a, float b) {
    return (u32)f2b(a) | ((u32)f2b(b) << 16);
}
__device__ __forceinline__ void load_lds16(const void* g, void* l) {
    __builtin_amdgcn_global_load_lds((const __attribute__((address_space(1))) void*)g,
                                     (__attribute__((address_space(3))) void*)l, 16, 0, 0);
}

// ---------------- CSR build ----------------

__global__ void count_deg(const int* __restrict__ dst, int* __restrict__ deg, int nE) {
    int e = blockIdx.x * 256 + threadIdx.x;
    if (e < nE) atomicAdd(&deg[dst[e]], 1);
}

__global__ void scan_block(const int* __restrict__ deg, int* __restrict__ row_start,
                           int* __restrict__ bsum, int n) {
    __shared__ int wtot[4];
    int i = blockIdx.x * 256 + threadIdx.x;
    int lane = threadIdx.x & 63, w = threadIdx.x >> 6;
    int v = (i < n) ? deg[i] : 0;
    int s = v;
#pragma unroll
    for (int d = 1; d < 64; d <<= 1) {
        int t = __shfl_up(s, d);
        if (lane >= d) s += t;
    }
    if (lane == 63) wtot[w] = s;
    __syncthreads();
    int off = 0;
#pragma unroll
    for (int k = 0; k < 4; ++k)
        if (k < w) off += wtot[k];
    s += off;
    if (i < n) row_start[i + 1] = s;
    if (threadIdx.x == 255) bsum[blockIdx.x] = s;
}

__global__ void scan_partials(const int* __restrict__ bsum, int* __restrict__ boff,
                              int* __restrict__ row_start, int* __restrict__ cursor, int nb) {
    __shared__ int wtot[4];
    int i = threadIdx.x;
    int lane = i & 63, w = i >> 6;
    int v = (i < nb) ? bsum[i] : 0;
    int s = v;
#pragma unroll
    for (int d = 1; d < 64; d <<= 1) {
        int t = __shfl_up(s, d);
        if (lane >= d) s += t;
    }
    if (lane == 63) wtot[w] = s;
    __syncthreads();
    int off = 0;
#pragma unroll
    for (int k = 0; k < 4; ++k)
        if (k < w) off += wtot[k];
    boff[i] = s + off - v;  // exclusive prefix of block sums
    if (i == 0) { row_start[0] = 0; cursor[0] = 0; }
}

__global__ void add_offsets(int* __restrict__ row_start, int* __restrict__ cursor,
                            const int* __restrict__ boff, int n) {
    int i = blockIdx.x * 256 + threadIdx.x;
    if (i < n) {
        int fin = row_start[i + 1] + boff[blockIdx.x];
        row_start[i + 1] = fin;
        cursor[i + 1] = fin;
    }
}

__global__ void fill_csr(const int* __restrict__ src, const int* __restrict__ dst,
                         int* __restrict__ cursor, int* __restrict__ srcs, int nE) {
    int e = blockIdx.x * 256 + threadIdx.x;
    if (e < nE) {
        int p = atomicAdd(&cursor[dst[e]], 1);
        srcs[p] = src[e];
    }
}

__global__ void graph_bounds(const int* __restrict__ batch, int* __restrict__ gstart,
                             int n, int ngraphs) {
    int g = blockIdx.x * 256 + threadIdx.x;
    if (g > ngraphs) return;
    int lo = 0, hi = n;
    while (lo < hi) {
        int mid = (lo + hi) >> 1;
        if (batch[mid] < g) lo = mid + 1; else hi = mid;
    }
    gstart[g] = lo;
}

// ---------------- converts ----------------

__global__ void convert_x4(const float4* __restrict__ in, uint2* __restrict__ out, int n4) {
    int i = blockIdx.x * 256 + threadIdx.x;
    if (i < n4) {
        float4 v = in[i];
        uint2 p;
        p.x = pack2(v.x, v.y);
        p.y = pack2(v.z, v.w);
        out[i] = p;
    }
}

// wt[n*K + k] = bf16(w[k*256 + n])   (transpose so B is K-contiguous)
__global__ void conv_wt(const float* __restrict__ w, u16* __restrict__ wt, int K) {
    int idx = blockIdx.x * 256 + threadIdx.x;
    if (idx >= 256 * K) return;
    int nn = idx / K, kk = idx - nn * K;
    wt[idx] = f2b(w[(size_t)kk * 256 + nn]);
}

// ---------------- aggregation (bf16 gather): agg = h_i + sum_j h_j ----------------

template <int F>
__global__ void aggregate_bf16(const u16* __restrict__ h, const int* __restrict__ row_start,
                               const int* __restrict__ srcs, u16* __restrict__ outp, int n) {
    constexpr int NWD = F / 128;  // uints per lane (1 or 2)
    int node = (int)(((size_t)blockIdx.x * blockDim.x + threadIdx.x) >> 6);
    int lane = threadIdx.x & 63;
    if (node >= n) return;
    const u32* base = (const u32*)h;
    int cw = lane * NWD;
    float acc[2 * NWD];
    u32 v0[NWD];
#pragma unroll
    for (int t = 0; t < NWD; ++t) v0[t] = base[(size_t)node * (F / 2) + cw + t];
#pragma unroll
    for (int t = 0; t < NWD; ++t) { acc[2 * t] = blo(v0[t]); acc[2 * t + 1] = bhi(v0[t]); }
    int s = row_start[node], e = row_start[node + 1];
    int j = s;
    for (; j + 1 < e; j += 2) {
        int s0 = srcs[j], s1 = srcs[j + 1];
        u32 a0[NWD], a1[NWD];
#pragma unroll
        for (int t = 0; t < NWD; ++t) a0[t] = base[(size_t)s0 * (F / 2) + cw + t];
#pragma unroll
        for (int t = 0; t < NWD; ++t) a1[t] = base[(size_t)s1 * (F / 2) + cw + t];
#pragma unroll
        for (int t = 0; t < NWD; ++t) {
            acc[2 * t] += blo(a0[t]) + blo(a1[t]);
            acc[2 * t + 1] += bhi(a0[t]) + bhi(a1[t]);
        }
    }
    if (j < e) {
        int s0 = srcs[j];
        u32 a0[NWD];
#pragma unroll
        for (int t = 0; t < NWD; ++t) a0[t] = base[(size_t)s0 * (F / 2) + cw + t];
#pragma unroll
        for (int t = 0; t < NWD; ++t) {
            acc[2 * t] += blo(a0[t]);
            acc[2 * t + 1] += bhi(a0[t]);
        }
    }
    u32* op = (u32*)outp;
#pragma unroll
    for (int t = 0; t < NWD; ++t)
        op[(size_t)node * (F / 2) + cw + t] = pack2(acc[2 * t], acc[2 * t + 1]);
}

// ---------------- bf16 MFMA GEMM: C = relu(A @ Wt^T + bias) ----------------
// A: M x K bf16 row-major; Wt: 256 x K bf16 (n-major, K-contiguous)
// block = 256 thr = 4 waves (2x2), tile 128x128, wave tile 64x64 (4x4 frags 16x16x32)
// MODE 0: C bf16 out.  MODE 1: C fp32 out + fused BN partial sums.

template <int MODE>
__global__ __launch_bounds__(256) void gemm_mfma(
    const u16* __restrict__ A, const u16* __restrict__ Bt, const float* __restrict__ bias,
    void* __restrict__ Cout, float* __restrict__ sums, int M, int K) {
    __shared__ u16 As[128 * 32];
    __shared__ u16 Bs[128 * 32];
    const int tid = threadIdx.x;
    const int w = tid >> 6, lane = tid & 63;
    const int wm = w >> 1, wn = w & 1;
    const int r = lane & 15, rg = lane >> 4;
    const int bm = blockIdx.x * 128;
    const int bn = blockIdx.y * 128;

    floatx4 acc[4][4];
#pragma unroll
    for (int i = 0; i < 4; ++i)
#pragma unroll
        for (int j = 0; j < 4; ++j) acc[i][j] = (floatx4){0.f, 0.f, 0.f, 0.f};

    for (int k0 = 0; k0 < K; k0 += 32) {
        __syncthreads();
#pragma unroll
        for (int q = 0; q < 2; ++q) {
            int i = q * 256 + tid;
            int ar = bm + (i >> 2);
            if (ar >= M) ar = M - 1;
            load_lds16(A + (size_t)ar * K + k0 + (i & 3) * 8, As + (q * 4 + w) * 512);
            int nr = bn + (i >> 2);
            load_lds16(Bt + (size_t)nr * K + k0 + (i & 3) * 8, Bs + (q * 4 + w) * 512);
        }
        __syncthreads();
        short8 a[4], b[4];
#pragma unroll
        for (int mi = 0; mi < 4; ++mi)
            a[mi] = *(const short8*)(As + (wm * 64 + mi * 16 + r) * 32 + rg * 8);
#pragma unroll
        for (int ni = 0; ni < 4; ++ni)
            b[ni] = *(const short8*)(Bs + (wn * 64 + ni * 16 + r) * 32 + rg * 8);
#pragma unroll
        for (int mi = 0; mi < 4; ++mi)
#pragma unroll
            for (int ni = 0; ni < 4; ++ni)
                acc[mi][ni] = __builtin_amdgcn_mfma_f32_16x16x32_bf16(a[mi], b[ni], acc[mi][ni], 0, 0, 0);
    }

    if (MODE == 0) {
        u16* C = (u16*)Cout;
#pragma unroll
        for (int ni = 0; ni < 4; ++ni) {
            int col = bn + wn * 64 + ni * 16 + r;
            float bv = bias[col];
#pragma unroll
            for (int mi = 0; mi < 4; ++mi)
#pragma unroll
                for (int rr = 0; rr < 4; ++rr) {
                    int row = bm + wm * 64 + mi * 16 + rg * 4 + rr;
                    if (row < M) C[(size_t)row * 256 + col] = f2b(fmaxf(acc[mi][ni][rr] + bv, 0.f));
                }
        }
    } else {
        float* C = (float*)Cout;
#pragma unroll
        for (int ni = 0; ni < 4; ++ni) {
            int col = bn + wn * 64 + ni * 16 + r;
            float bv = bias[col];
            float s = 0.f, s2 = 0.f;
#pragma unroll
            for (int mi = 0; mi < 4; ++mi)
#pragma unroll
                for (int rr = 0; rr < 4; ++rr) {
                    int row = bm + wm * 64 + mi * 16 + rg * 4 + rr;
                    if (row < M) {
                        float v = fmaxf(acc[mi][ni][rr] + bv, 0.f);
                        C[(size_t)row * 256 + col] = v;
                        s += v;
                        s2 += v * v;
                    }
                }
            s += __shfl_xor(s, 16);
            s += __shfl_xor(s, 32);
            s2 += __shfl_xor(s2, 16);
            s2 += __shfl_xor(s2, 32);
            if (rg == 0) {
                atomicAdd(&sums[col], s);
                atomicAdd(&sums[256 + col], s2);
            }
        }
    }
}

// ---------------- batchnorm ----------------

__global__ void bn_finalize(const float* __restrict__ sums, const float* __restrict__ g,
                            const float* __restrict__ b, float* __restrict__ ss, float inv_n) {
    int c = threadIdx.x;
    float mu = sums[c] * inv_n;
    float var = sums[256 + c] * inv_n - mu * mu;
    float sc = g[c] / sqrtf(var + BN_EPS);
    ss[c] = sc;
    ss[256 + c] = b[c] - mu * sc;
}

__global__ void bn_apply(const float* __restrict__ m, const float* __restrict__ ss,
                         float* __restrict__ out_nodes, u16* __restrict__ hb, int n, int col_off) {
    int idx = blockIdx.x * 256 + threadIdx.x;
    if (idx >= n * 64) return;
    int row = idx >> 6;
    int c4 = (idx & 63) << 2;
    float4 v = *(const float4*)(m + (size_t)row * 256 + c4);
    float4 sc = *(const float4*)(ss + c4);
    float4 sh = *(const float4*)(ss + 256 + c4);
    float4 o;
    o.x = fmaf(v.x, sc.x, sh.x);
    o.y = fmaf(v.y, sc.y, sh.y);
    o.z = fmaf(v.z, sc.z, sh.z);
    o.w = fmaf(v.w, sc.w, sh.w);
    *(float4*)(out_nodes + (size_t)row * 768 + col_off + c4) = o;
    uint2 pk;
    pk.x = pack2(o.x, o.y);
    pk.y = pack2(o.z, o.w);
    *(uint2*)(hb + (size_t)row * 256 + c4) = pk;
}

// ---------------- per-graph add pool ----------------

__global__ void pool_graphs(const float* __restrict__ out_nodes, const int* __restrict__ gstart,
                            float* __restrict__ pooled) {
    int g = blockIdx.x;
    int c = threadIdx.x;
    float a0 = 0.f, a1 = 0.f, a2 = 0.f;
    int s = gstart[g], e = gstart[g + 1];
    for (int i = s; i < e; ++i) {
        const float* rr = out_nodes + (size_t)i * 768;
        a0 += rr[c];
        a1 += rr[c + 256];
        a2 += rr[c + 512];
    }
    pooled[(size_t)g * 768 + c] = a0;
    pooled[(size_t)g * 768 + c + 256] = a1;
    pooled[(size_t)g * 768 + c + 512] = a2;
}

// ---------------- launch ----------------

extern "C" void kernel_launch(void* const* d_in, const int* in_sizes, int n_in,
                              void* d_out, int out_size, void* d_ws, size_t ws_size,
                              hipStream_t stream) {
    const float* x = (const float*)d_in[0];
    const int* esrc = (const int*)d_in[1];
    const int* edst = esrc + N_EDGES;
    const int* batch = (const int*)d_in[2];

    const float* w1[3] = {(const float*)d_in[3], (const float*)d_in[9], (const float*)d_in[15]};
    const float* b1[3] = {(const float*)d_in[4], (const float*)d_in[10], (const float*)d_in[16]};
    const float* w2[3] = {(const float*)d_in[5], (const float*)d_in[11], (const float*)d_in[17]};
    const float* b2[3] = {(const float*)d_in[6], (const float*)d_in[12], (const float*)d_in[18]};
    const float* bng[3] = {(const float*)d_in[7], (const float*)d_in[13], (const float*)d_in[19]};
    const float* bnb[3] = {(const float*)d_in[8], (const float*)d_in[14], (const float*)d_in[20]};

    float* out_pooled = (float*)d_out;
    float* out_nodes = (float*)d_out + (size_t)N_GRAPHS * 768;

    char* p = (char*)d_ws;
    float* Mfp = (float*)p;            // 50000*256 fp32  (GEMM2 out)
    u16* Abf = (u16*)p;                // 50000*256 bf16  (aliases Mfp's first half; disjoint in time)
    p += (size_t)N_NODES * 256 * 4;
    u16* T = (u16*)p;  p += (size_t)N_NODES * 256 * 2;   // GEMM1 out
    u16* H = (u16*)p;  p += (size_t)N_NODES * 256 * 2;   // bf16 node feats (x_bf16 first 128 cols for L0)
    u16* W1t[3]; u16* W2t[3];
    W1t[0] = (u16*)p; p += 256 * 128 * 2;
    W1t[1] = (u16*)p; p += 256 * 256 * 2;
    W1t[2] = (u16*)p; p += 256 * 256 * 2;
    for (int L = 0; L < 3; ++L) { W2t[L] = (u16*)p; p += 256 * 256 * 2; }
    float* sums = (float*)p; p += 512 * 4;
    float* ss = (float*)p;   p += 512 * 4;
    int* deg = (int*)p;       p += (size_t)N_NODES * 4;
    int* row_start = (int*)p; p += (size_t)(N_NODES + 1) * 4;
    int* cursor = (int*)p;    p += (size_t)(N_NODES + 1) * 4;
    int* srcs = (int*)p;      p += (size_t)N_EDGES * 4;
    int* gstart = (int*)p;    p += (size_t)(N_GRAPHS + 1) * 4;
    int* bsum = (int*)p;      p += 256 * 4;
    int* boff = (int*)p;      p += 256 * 4;

    const int NBLK = (N_NODES + 255) / 256;  // 196

    // CSR build
    hipMemsetAsync(deg, 0, N_NODES * sizeof(int), stream);
    count_deg<<<(N_EDGES + 255) / 256, 256, 0, stream>>>(edst, deg, N_EDGES);
    scan_block<<<NBLK, 256, 0, stream>>>(deg, row_start, bsum, N_NODES);
    scan_partials<<<1, 256, 0, stream>>>(bsum, boff, row_start, cursor, NBLK);
    add_offsets<<<NBLK, 256, 0, stream>>>(row_start, cursor, boff, N_NODES);
    fill_csr<<<(N_EDGES + 255) / 256, 256, 0, stream>>>(esrc, edst, cursor, srcs, N_EDGES);
    graph_bounds<<<3, 256, 0, stream>>>(batch, gstart, N_NODES, N_GRAPHS);

    // converts
    convert_x4<<<(N_NODES * F_IN / 4 + 255) / 256, 256, 0, stream>>>(
        (const float4*)x, (uint2*)H, N_NODES * F_IN / 4);
    for (int L = 0; L < 3; ++L) {
        int K1 = (L == 0) ? F_IN : DIM;
        conv_wt<<<(256 * K1 + 255) / 256, 256, 0, stream>>>(w1[L], W1t[L], K1);
        conv_wt<<<(256 * 256 + 255) / 256, 256, 0, stream>>>(w2[L], W2t[L], 256);
    }

    dim3 ggrid((N_NODES + 127) / 128, 2);
    for (int L = 0; L < 3; ++L) {
        int K1 = (L == 0) ? F_IN : DIM;
        if (L == 0)
            aggregate_bf16<128><<<(N_NODES + 3) / 4, 256, 0, stream>>>(H, row_start, srcs, Abf, N_NODES);
        else
            aggregate_bf16<256><<<(N_NODES + 3) / 4, 256, 0, stream>>>(H, row_start, srcs, Abf, N_NODES);
        gemm_mfma<0><<<ggrid, 256, 0, stream>>>(Abf, W1t[L], b1[L], (void*)T, nullptr, N_NODES, K1);
        hipMemsetAsync(sums, 0, 512 * sizeof(float), stream);
        gemm_mfma<1><<<ggrid, 256, 0, stream>>>(T, W2t[L], b2[L], (void*)Mfp, sums, N_NODES, DIM);
        bn_finalize<<<1, 256, 0, stream>>>(sums, bng[L], bnb[L], ss, 1.0f / N_NODES);
        bn_apply<<<(N_NODES * 64 + 255) / 256, 256, 0, stream>>>(Mfp, ss, out_nodes, H, N_NODES, L * 256);
    }
    pool_graphs<<<N_GRAPHS, 256, 0, stream>>>(out_nodes, gstart, out_pooled);
}

// Round 3
// 803.619 us; speedup vs baseline: 1.9476x; 1.0323x over previous
//
#include <hip/hip_runtime.h>

#define N_NODES 50000
#define N_EDGES 800000
#define F_IN 128
#define DIM 256
#define N_GRAPHS 512
#define BN_EPS 1e-5f

typedef unsigned short u16;
typedef unsigned int u32;
using floatx4 = __attribute__((ext_vector_type(4))) float;
using short8 = __attribute__((ext_vector_type(8))) short;

__device__ __forceinline__ u16 f2b(float f) {
    u32 u = __float_as_uint(f);
    return (u16)((u + 0x7fffu + ((u >> 16) & 1u)) >> 16);
}
__device__ __forceinline__ float blo(u32 u) { return __uint_as_float(u << 16); }
__device__ __forceinline__ float bhi(u32 u) { return __uint_as_float(u & 0xffff0000u); }
__device__ __forceinline__ u32 pack2(float a, float b) {
    return (u32)f2b(a) | ((u32)f2b(b) << 16);
}
__device__ __forceinline__ void load_lds16(const void* g, void* l) {
    __builtin_amdgcn_global_load_lds((const __attribute__((address_space(1))) void*)g,
                                     (__attribute__((address_space(3))) void*)l, 16, 0, 0);
}

// ---------------- CSR build ----------------

__global__ void count_deg(const int* __restrict__ dst, int* __restrict__ deg, int nE) {
    int e = blockIdx.x * 256 + threadIdx.x;
    if (e < nE) atomicAdd(&deg[dst[e]], 1);
}

__global__ void scan_block(const int* __restrict__ deg, int* __restrict__ row_start,
                           int* __restrict__ bsum, int n) {
    __shared__ int wtot[4];
    int i = blockIdx.x * 256 + threadIdx.x;
    int lane = threadIdx.x & 63, w = threadIdx.x >> 6;
    int v = (i < n) ? deg[i] : 0;
    int s = v;
#pragma unroll
    for (int d = 1; d < 64; d <<= 1) {
        int t = __shfl_up(s, d);
        if (lane >= d) s += t;
    }
    if (lane == 63) wtot[w] = s;
    __syncthreads();
    int off = 0;
#pragma unroll
    for (int k = 0; k < 4; ++k)
        if (k < w) off += wtot[k];
    s += off;
    if (i < n) row_start[i + 1] = s;
    if (threadIdx.x == 255) bsum[blockIdx.x] = s;
}

__global__ void scan_partials(const int* __restrict__ bsum, int* __restrict__ boff,
                              int* __restrict__ row_start, int* __restrict__ cursor, int nb) {
    __shared__ int wtot[4];
    int i = threadIdx.x;
    int lane = i & 63, w = i >> 6;
    int v = (i < nb) ? bsum[i] : 0;
    int s = v;
#pragma unroll
    for (int d = 1; d < 64; d <<= 1) {
        int t = __shfl_up(s, d);
        if (lane >= d) s += t;
    }
    if (lane == 63) wtot[w] = s;
    __syncthreads();
    int off = 0;
#pragma unroll
    for (int k = 0; k < 4; ++k)
        if (k < w) off += wtot[k];
    boff[i] = s + off - v;
    if (i == 0) { row_start[0] = 0; cursor[0] = 0; }
}

__global__ void add_offsets(int* __restrict__ row_start, int* __restrict__ cursor,
                            const int* __restrict__ boff, int n) {
    int i = blockIdx.x * 256 + threadIdx.x;
    if (i < n) {
        int fin = row_start[i + 1] + boff[blockIdx.x];
        row_start[i + 1] = fin;
        cursor[i + 1] = fin;
    }
}

__global__ void fill_csr(const int* __restrict__ src, const int* __restrict__ dst,
                         int* __restrict__ cursor, int* __restrict__ srcs, int nE) {
    int e = blockIdx.x * 256 + threadIdx.x;
    if (e < nE) {
        int p = atomicAdd(&cursor[dst[e]], 1);
        srcs[p] = src[e];
    }
}

// ---------------- converts ----------------

__global__ void convert_x4(const float4* __restrict__ in, uint2* __restrict__ out, int n4) {
    int i = blockIdx.x * 256 + threadIdx.x;
    if (i < n4) {
        float4 v = in[i];
        uint2 p;
        p.x = pack2(v.x, v.y);
        p.y = pack2(v.z, v.w);
        out[i] = p;
    }
}

__global__ void conv_wt(const float* __restrict__ w, u16* __restrict__ wt, int K) {
    int idx = blockIdx.x * 256 + threadIdx.x;
    if (idx >= 256 * K) return;
    int nn = idx / K, kk = idx - nn * K;
    wt[idx] = f2b(w[(size_t)kk * 256 + nn]);
}

// ---------------- aggregation (bf16 gather): agg = h_i + sum_j h_j ----------------
// one wave per node. Indices pre-loaded cooperatively (one coalesced load for up
// to 64 neighbors), broadcast by __shfl -> row gathers issue back-to-back.

template <int F>
__global__ void aggregate_bf16(const u16* __restrict__ h, const int* __restrict__ row_start,
                               const int* __restrict__ srcs, u16* __restrict__ outp, int n) {
    constexpr int NWD = F / 128;  // uints per lane (1 or 2)
    int node = (int)(((size_t)blockIdx.x * blockDim.x + threadIdx.x) >> 6);
    int lane = threadIdx.x & 63;
    if (node >= n) return;
    const u32* base = (const u32*)h;
    int cw = lane * NWD;
    float acc[2 * NWD];
#pragma unroll
    for (int t = 0; t < NWD; ++t) {
        u32 v0 = base[(size_t)node * (F / 2) + cw + t];
        acc[2 * t] = blo(v0);
        acc[2 * t + 1] = bhi(v0);
    }
    int s = row_start[node], e = row_start[node + 1];
    for (int j0 = s; j0 < e; j0 += 64) {
        int myidx = (j0 + lane < e) ? srcs[j0 + lane] : 0;
        int cnt = min(64, e - j0);
        int j = 0;
        for (; j + 3 < cnt; j += 4) {
            int s0 = __shfl(myidx, j);
            int s1 = __shfl(myidx, j + 1);
            int s2 = __shfl(myidx, j + 2);
            int s3 = __shfl(myidx, j + 3);
            u32 a0[NWD], a1[NWD], a2[NWD], a3[NWD];
#pragma unroll
            for (int t = 0; t < NWD; ++t) a0[t] = base[(size_t)s0 * (F / 2) + cw + t];
#pragma unroll
            for (int t = 0; t < NWD; ++t) a1[t] = base[(size_t)s1 * (F / 2) + cw + t];
#pragma unroll
            for (int t = 0; t < NWD; ++t) a2[t] = base[(size_t)s2 * (F / 2) + cw + t];
#pragma unroll
            for (int t = 0; t < NWD; ++t) a3[t] = base[(size_t)s3 * (F / 2) + cw + t];
#pragma unroll
            for (int t = 0; t < NWD; ++t) {
                acc[2 * t]     += (blo(a0[t]) + blo(a1[t])) + (blo(a2[t]) + blo(a3[t]));
                acc[2 * t + 1] += (bhi(a0[t]) + bhi(a1[t])) + (bhi(a2[t]) + bhi(a3[t]));
            }
        }
        for (; j < cnt; ++j) {
            int s0 = __shfl(myidx, j);
            u32 a0[NWD];
#pragma unroll
            for (int t = 0; t < NWD; ++t) a0[t] = base[(size_t)s0 * (F / 2) + cw + t];
#pragma unroll
            for (int t = 0; t < NWD; ++t) {
                acc[2 * t] += blo(a0[t]);
                acc[2 * t + 1] += bhi(a0[t]);
            }
        }
    }
    u32* op = (u32*)outp;
#pragma unroll
    for (int t = 0; t < NWD; ++t)
        op[(size_t)node * (F / 2) + cw + t] = pack2(acc[2 * t], acc[2 * t + 1]);
}

// ---------------- bf16 MFMA GEMM: C = relu(A @ Wt^T + bias) ----------------

template <int MODE>
__global__ __launch_bounds__(256) void gemm_mfma(
    const u16* __restrict__ A, const u16* __restrict__ Bt, const float* __restrict__ bias,
    void* __restrict__ Cout, float* __restrict__ sums, int M, int K) {
    __shared__ u16 As[128 * 32];
    __shared__ u16 Bs[128 * 32];
    const int tid = threadIdx.x;
    const int w = tid >> 6, lane = tid & 63;
    const int wm = w >> 1, wn = w & 1;
    const int r = lane & 15, rg = lane >> 4;
    const int bm = blockIdx.x * 128;
    const int bn = blockIdx.y * 128;

    floatx4 acc[4][4];
#pragma unroll
    for (int i = 0; i < 4; ++i)
#pragma unroll
        for (int j = 0; j < 4; ++j) acc[i][j] = (floatx4){0.f, 0.f, 0.f, 0.f};

    for (int k0 = 0; k0 < K; k0 += 32) {
        __syncthreads();
#pragma unroll
        for (int q = 0; q < 2; ++q) {
            int i = q * 256 + tid;
            int ar = bm + (i >> 2);
            if (ar >= M) ar = M - 1;
            load_lds16(A + (size_t)ar * K + k0 + (i & 3) * 8, As + (q * 4 + w) * 512);
            int nr = bn + (i >> 2);
            load_lds16(Bt + (size_t)nr * K + k0 + (i & 3) * 8, Bs + (q * 4 + w) * 512);
        }
        __syncthreads();
        short8 a[4], b[4];
#pragma unroll
        for (int mi = 0; mi < 4; ++mi)
            a[mi] = *(const short8*)(As + (wm * 64 + mi * 16 + r) * 32 + rg * 8);
#pragma unroll
        for (int ni = 0; ni < 4; ++ni)
            b[ni] = *(const short8*)(Bs + (wn * 64 + ni * 16 + r) * 32 + rg * 8);
#pragma unroll
        for (int mi = 0; mi < 4; ++mi)
#pragma unroll
            for (int ni = 0; ni < 4; ++ni)
                acc[mi][ni] = __builtin_amdgcn_mfma_f32_16x16x32_bf16(a[mi], b[ni], acc[mi][ni], 0, 0, 0);
    }

    if (MODE == 0) {
        u16* C = (u16*)Cout;
#pragma unroll
        for (int ni = 0; ni < 4; ++ni) {
            int col = bn + wn * 64 + ni * 16 + r;
            float bv = bias[col];
#pragma unroll
            for (int mi = 0; mi < 4; ++mi)
#pragma unroll
                for (int rr = 0; rr < 4; ++rr) {
                    int row = bm + wm * 64 + mi * 16 + rg * 4 + rr;
                    if (row < M) C[(size_t)row * 256 + col] = f2b(fmaxf(acc[mi][ni][rr] + bv, 0.f));
                }
        }
    } else {
        float* C = (float*)Cout;
#pragma unroll
        for (int ni = 0; ni < 4; ++ni) {
            int col = bn + wn * 64 + ni * 16 + r;
            float bv = bias[col];
            float s = 0.f, s2 = 0.f;
#pragma unroll
            for (int mi = 0; mi < 4; ++mi)
#pragma unroll
                for (int rr = 0; rr < 4; ++rr) {
                    int row = bm + wm * 64 + mi * 16 + rg * 4 + rr;
                    if (row < M) {
                        float v = fmaxf(acc[mi][ni][rr] + bv, 0.f);
                        C[(size_t)row * 256 + col] = v;
                        s += v;
                        s2 += v * v;
                    }
                }
            s += __shfl_xor(s, 16);
            s += __shfl_xor(s, 32);
            s2 += __shfl_xor(s2, 16);
            s2 += __shfl_xor(s2, 32);
            if (rg == 0) {
                atomicAdd(&sums[col], s);
                atomicAdd(&sums[256 + col], s2);
            }
        }
    }
}

// ---------------- batchnorm finalize ----------------

__global__ void bn_finalize(const float* __restrict__ sums, const float* __restrict__ g,
                            const float* __restrict__ b, float* __restrict__ ss, float inv_n) {
    int c = threadIdx.x;
    float mu = sums[c] * inv_n;
    float var = sums[256 + c] * inv_n - mu * mu;
    float sc = g[c] / sqrtf(var + BN_EPS);
    ss[c] = sc;
    ss[256 + c] = b[c] - mu * sc;
}

// ---------------- BN apply + bf16 re-pack + fused per-graph pooling ----------------
// one wave per 16 consecutive rows; batch sorted -> register pool accumulator,
// flushed by atomics on graph change (~1 flush/wave on average)

template <int WRITE_H>
__global__ void bn_apply_pool(const float* __restrict__ Mfp, const float* __restrict__ ss,
                              const int* __restrict__ batch, float* __restrict__ out_nodes,
                              u16* __restrict__ H, float* __restrict__ pooled,
                              int col_off, int n) {
    int w = threadIdx.x >> 6, lane = threadIdx.x & 63;
    int base = blockIdx.x * 64 + w * 16;
    if (base >= n) return;
    int c4 = lane << 2;
    float4 sc = *(const float4*)(ss + c4);
    float4 sh = *(const float4*)(ss + 256 + c4);
    float4 acc = make_float4(0.f, 0.f, 0.f, 0.f);
    int gcur = -1;
    int end = min(base + 16, n);
    for (int row = base; row < end; ++row) {
        float4 v = *(const float4*)(Mfp + (size_t)row * 256 + c4);
        float4 o;
        o.x = fmaf(v.x, sc.x, sh.x);
        o.y = fmaf(v.y, sc.y, sh.y);
        o.z = fmaf(v.z, sc.z, sh.z);
        o.w = fmaf(v.w, sc.w, sh.w);
        *(float4*)(out_nodes + (size_t)row * 768 + col_off + c4) = o;
        if (WRITE_H) {
            uint2 pk;
            pk.x = pack2(o.x, o.y);
            pk.y = pack2(o.z, o.w);
            *(uint2*)(H + (size_t)row * 256 + c4) = pk;
        }
        int g = batch[row];
        if (g != gcur) {
            if (gcur >= 0) {
                float* pp = pooled + (size_t)gcur * 768 + col_off + c4;
                atomicAdd(pp + 0, acc.x);
                atomicAdd(pp + 1, acc.y);
                atomicAdd(pp + 2, acc.z);
                atomicAdd(pp + 3, acc.w);
            }
            gcur = g;
            acc = o;
        } else {
            acc.x += o.x; acc.y += o.y; acc.z += o.z; acc.w += o.w;
        }
    }
    if (gcur >= 0) {
        float* pp = pooled + (size_t)gcur * 768 + col_off + c4;
        atomicAdd(pp + 0, acc.x);
        atomicAdd(pp + 1, acc.y);
        atomicAdd(pp + 2, acc.z);
        atomicAdd(pp + 3, acc.w);
    }
}

// ---------------- launch ----------------

extern "C" void kernel_launch(void* const* d_in, const int* in_sizes, int n_in,
                              void* d_out, int out_size, void* d_ws, size_t ws_size,
                              hipStream_t stream) {
    const float* x = (const float*)d_in[0];
    const int* esrc = (const int*)d_in[1];
    const int* edst = esrc + N_EDGES;
    const int* batch = (const int*)d_in[2];

    const float* w1[3] = {(const float*)d_in[3], (const float*)d_in[9], (const float*)d_in[15]};
    const float* b1[3] = {(const float*)d_in[4], (const float*)d_in[10], (const float*)d_in[16]};
    const float* w2[3] = {(const float*)d_in[5], (const float*)d_in[11], (const float*)d_in[17]};
    const float* b2[3] = {(const float*)d_in[6], (const float*)d_in[12], (const float*)d_in[18]};
    const float* bng[3] = {(const float*)d_in[7], (const float*)d_in[13], (const float*)d_in[19]};
    const float* bnb[3] = {(const float*)d_in[8], (const float*)d_in[14], (const float*)d_in[20]};

    float* out_pooled = (float*)d_out;
    float* out_nodes = (float*)d_out + (size_t)N_GRAPHS * 768;

    char* p = (char*)d_ws;
    float* Mfp = (float*)p;            // 50000*256 fp32 (GEMM2 out)
    u16* Abf = (u16*)p;                // aliases Mfp (disjoint in time)
    p += (size_t)N_NODES * 256 * 4;
    u16* T = (u16*)p;  p += (size_t)N_NODES * 256 * 2;   // GEMM1 out
    u16* H = (u16*)p;  p += (size_t)N_NODES * 256 * 2;   // bf16 node feats
    u16* W1t[3]; u16* W2t[3];
    W1t[0] = (u16*)p; p += 256 * 128 * 2;
    W1t[1] = (u16*)p; p += 256 * 256 * 2;
    W1t[2] = (u16*)p; p += 256 * 256 * 2;
    for (int L = 0; L < 3; ++L) { W2t[L] = (u16*)p; p += 256 * 256 * 2; }
    float* sums = (float*)p; p += 512 * 4;
    float* ss = (float*)p;   p += 512 * 4;
    int* deg = (int*)p;       p += (size_t)N_NODES * 4;
    int* row_start = (int*)p; p += (size_t)(N_NODES + 1) * 4;
    int* cursor = (int*)p;    p += (size_t)(N_NODES + 1) * 4;
    int* srcs = (int*)p;      p += (size_t)N_EDGES * 4;
    int* bsum = (int*)p;      p += 256 * 4;
    int* boff = (int*)p;      p += 256 * 4;

    const int NBLK = (N_NODES + 255) / 256;  // 196

    // CSR build
    hipMemsetAsync(deg, 0, N_NODES * sizeof(int), stream);
    count_deg<<<(N_EDGES + 255) / 256, 256, 0, stream>>>(edst, deg, N_EDGES);
    scan_block<<<NBLK, 256, 0, stream>>>(deg, row_start, bsum, N_NODES);
    scan_partials<<<1, 256, 0, stream>>>(bsum, boff, row_start, cursor, NBLK);
    add_offsets<<<NBLK, 256, 0, stream>>>(row_start, cursor, boff, N_NODES);
    fill_csr<<<(N_EDGES + 255) / 256, 256, 0, stream>>>(esrc, edst, cursor, srcs, N_EDGES);

    // converts + zero pooled section of d_out
    hipMemsetAsync(out_pooled, 0, (size_t)N_GRAPHS * 768 * sizeof(float), stream);
    convert_x4<<<(N_NODES * F_IN / 4 + 255) / 256, 256, 0, stream>>>(
        (const float4*)x, (uint2*)H, N_NODES * F_IN / 4);
    for (int L = 0; L < 3; ++L) {
        int K1 = (L == 0) ? F_IN : DIM;
        conv_wt<<<(256 * K1 + 255) / 256, 256, 0, stream>>>(w1[L], W1t[L], K1);
        conv_wt<<<(256 * 256 + 255) / 256, 256, 0, stream>>>(w2[L], W2t[L], 256);
    }

    dim3 ggrid((N_NODES + 127) / 128, 2);
    const int PBLK = (N_NODES + 63) / 64;  // 782
    for (int L = 0; L < 3; ++L) {
        int K1 = (L == 0) ? F_IN : DIM;
        if (L == 0)
            aggregate_bf16<128><<<(N_NODES + 3) / 4, 256, 0, stream>>>(H, row_start, srcs, Abf, N_NODES);
        else
            aggregate_bf16<256><<<(N_NODES + 3) / 4, 256, 0, stream>>>(H, row_start, srcs, Abf, N_NODES);
        gemm_mfma<0><<<ggrid, 256, 0, stream>>>(Abf, W1t[L], b1[L], (void*)T, nullptr, N_NODES, K1);
        hipMemsetAsync(sums, 0, 512 * sizeof(float), stream);
        gemm_mfma<1><<<ggrid, 256, 0, stream>>>(T, W2t[L], b2[L], (void*)Mfp, sums, N_NODES, DIM);
        bn_finalize<<<1, 256, 0, stream>>>(sums, bng[L], bnb[L], ss, 1.0f / N_NODES);
        if (L < 2)
            bn_apply_pool<1><<<PBLK, 256, 0, stream>>>(Mfp, ss, batch, out_nodes, H, out_pooled, L * 256, N_NODES);
        else
            bn_apply_pool<0><<<PBLK, 256, 0, stream>>>(Mfp, ss, batch, out_nodes, H, out_pooled, L * 256, N_NODES);
    }
}

// Round 4
// 723.157 us; speedup vs baseline: 2.1643x; 1.1113x over previous
//
#include <hip/hip_runtime.h>

#define N_NODES 50000
#define N_EDGES 800000
#define F_IN 128
#define DIM 256
#define N_GRAPHS 512
#define BN_EPS 1e-5f

typedef unsigned short u16;
typedef unsigned int u32;
using floatx4 = __attribute__((ext_vector_type(4))) float;
using short8 = __attribute__((ext_vector_type(8))) short;

__device__ __forceinline__ u16 f2b(float f) {
    u32 u = __float_as_uint(f);
    return (u16)((u + 0x7fffu + ((u >> 16) & 1u)) >> 16);
}
__device__ __forceinline__ float blo(u32 u) { return __uint_as_float(u << 16); }
__device__ __forceinline__ float bhi(u32 u) { return __uint_as_float(u & 0xffff0000u); }
__device__ __forceinline__ u32 pack2(float a, float b) {
    return (u32)f2b(a) | ((u32)f2b(b) << 16);
}
__device__ __forceinline__ void load_lds16(const void* g, void* l) {
    __builtin_amdgcn_global_load_lds((const __attribute__((address_space(1))) void*)g,
                                     (__attribute__((address_space(3))) void*)l, 16, 0, 0);
}

// ---------------- CSR build ----------------

__global__ void count_deg(const int* __restrict__ dst, int* __restrict__ deg, int nE) {
    int e = blockIdx.x * 256 + threadIdx.x;
    if (e < nE) atomicAdd(&deg[dst[e]], 1);
}

__global__ void scan_block(const int* __restrict__ deg, int* __restrict__ row_start,
                           int* __restrict__ bsum, int n) {
    __shared__ int wtot[4];
    int i = blockIdx.x * 256 + threadIdx.x;
    int lane = threadIdx.x & 63, w = threadIdx.x >> 6;
    int v = (i < n) ? deg[i] : 0;
    int s = v;
#pragma unroll
    for (int d = 1; d < 64; d <<= 1) {
        int t = __shfl_up(s, d);
        if (lane >= d) s += t;
    }
    if (lane == 63) wtot[w] = s;
    __syncthreads();
    int off = 0;
#pragma unroll
    for (int k = 0; k < 4; ++k)
        if (k < w) off += wtot[k];
    s += off;
    if (i < n) row_start[i + 1] = s;
    if (threadIdx.x == 255) bsum[blockIdx.x] = s;
}

__global__ void scan_partials(const int* __restrict__ bsum, int* __restrict__ boff,
                              int* __restrict__ row_start, int* __restrict__ cursor, int nb) {
    __shared__ int wtot[4];
    int i = threadIdx.x;
    int lane = i & 63, w = i >> 6;
    int v = (i < nb) ? bsum[i] : 0;
    int s = v;
#pragma unroll
    for (int d = 1; d < 64; d <<= 1) {
        int t = __shfl_up(s, d);
        if (lane >= d) s += t;
    }
    if (lane == 63) wtot[w] = s;
    __syncthreads();
    int off = 0;
#pragma unroll
    for (int k = 0; k < 4; ++k)
        if (k < w) off += wtot[k];
    boff[i] = s + off - v;
    if (i == 0) { row_start[0] = 0; cursor[0] = 0; }
}

__global__ void add_offsets(int* __restrict__ row_start, int* __restrict__ cursor,
                            const int* __restrict__ boff, int n) {
    int i = blockIdx.x * 256 + threadIdx.x;
    if (i < n) {
        int fin = row_start[i + 1] + boff[blockIdx.x];
        row_start[i + 1] = fin;
        cursor[i + 1] = fin;
    }
}

__global__ void fill_csr(const int* __restrict__ src, const int* __restrict__ dst,
                         int* __restrict__ cursor, int* __restrict__ srcs, int nE) {
    int e = blockIdx.x * 256 + threadIdx.x;
    if (e < nE) {
        int p = atomicAdd(&cursor[dst[e]], 1);
        srcs[p] = src[e];
    }
}

// ---------------- one-shot converts: x -> bf16 H, all 6 weights -> transposed bf16 ----------------
// segment bases (u16 elems in Wall): w1_0@0 (K=128), w1_1@32768, w1_2@98304,
// w2_0@163840, w2_1@229376, w2_2@294912 ; total 360448

__global__ void convert_all(const float4* __restrict__ x4, uint2* __restrict__ Hout, int n4,
                            const float* __restrict__ w10, const float* __restrict__ w11,
                            const float* __restrict__ w12, const float* __restrict__ w20,
                            const float* __restrict__ w21, const float* __restrict__ w22,
                            u16* __restrict__ Wall) {
    int i = blockIdx.x * 256 + threadIdx.x;
    if (i < n4) {
        float4 v = x4[i];
        uint2 p;
        p.x = pack2(v.x, v.y);
        p.y = pack2(v.z, v.w);
        Hout[i] = p;
        return;
    }
    int j = i - n4;
    if (j >= 360448) return;
    const float* w;
    int K, base;
    if (j < 32768)       { w = w10; K = 128; base = 0; }
    else if (j < 98304)  { w = w11; K = 256; base = 32768; }
    else if (j < 163840) { w = w12; K = 256; base = 98304; }
    else if (j < 229376) { w = w20; K = 256; base = 163840; }
    else if (j < 294912) { w = w21; K = 256; base = 229376; }
    else                 { w = w22; K = 256; base = 294912; }
    int loc = j - base;
    int nn = loc / K, kk = loc - nn * K;
    Wall[j] = f2b(w[(size_t)kk * 256 + nn]);
}

// ---------------- aggregation (bf16 gather): agg = h_i + sum_j h_j ----------------
// one wave per node; indices loaded coalesced then shfl-broadcast; 8-deep gather ILP

template <int F>
__global__ void aggregate_bf16(const u16* __restrict__ h, const int* __restrict__ row_start,
                               const int* __restrict__ srcs, u16* __restrict__ outp, int n) {
    constexpr int NWD = F / 128;  // uints per lane (1 or 2)
    int node = (int)(((size_t)blockIdx.x * blockDim.x + threadIdx.x) >> 6);
    int lane = threadIdx.x & 63;
    if (node >= n) return;
    const u32* base = (const u32*)h;
    int cw = lane * NWD;
    float acc[2 * NWD];
#pragma unroll
    for (int t = 0; t < NWD; ++t) {
        u32 v0 = base[(size_t)node * (F / 2) + cw + t];
        acc[2 * t] = blo(v0);
        acc[2 * t + 1] = bhi(v0);
    }
    int s = row_start[node], e = row_start[node + 1];
    for (int j0 = s; j0 < e; j0 += 64) {
        int myidx = (j0 + lane < e) ? srcs[j0 + lane] : 0;
        int cnt = min(64, e - j0);
        int j = 0;
        for (; j + 7 < cnt; j += 8) {
            u32 a[8][NWD];
#pragma unroll
            for (int q = 0; q < 8; ++q) {
                int sq = __shfl(myidx, j + q);
#pragma unroll
                for (int t = 0; t < NWD; ++t) a[q][t] = base[(size_t)sq * (F / 2) + cw + t];
            }
#pragma unroll
            for (int q = 0; q < 8; ++q)
#pragma unroll
                for (int t = 0; t < NWD; ++t) {
                    acc[2 * t] += blo(a[q][t]);
                    acc[2 * t + 1] += bhi(a[q][t]);
                }
        }
        for (; j + 3 < cnt; j += 4) {
            u32 a[4][NWD];
#pragma unroll
            for (int q = 0; q < 4; ++q) {
                int sq = __shfl(myidx, j + q);
#pragma unroll
                for (int t = 0; t < NWD; ++t) a[q][t] = base[(size_t)sq * (F / 2) + cw + t];
            }
#pragma unroll
            for (int q = 0; q < 4; ++q)
#pragma unroll
                for (int t = 0; t < NWD; ++t) {
                    acc[2 * t] += blo(a[q][t]);
                    acc[2 * t + 1] += bhi(a[q][t]);
                }
        }
        for (; j < cnt; ++j) {
            int s0 = __shfl(myidx, j);
            u32 a0[NWD];
#pragma unroll
            for (int t = 0; t < NWD; ++t) a0[t] = base[(size_t)s0 * (F / 2) + cw + t];
#pragma unroll
            for (int t = 0; t < NWD; ++t) {
                acc[2 * t] += blo(a0[t]);
                acc[2 * t + 1] += bhi(a0[t]);
            }
        }
    }
    u32* op = (u32*)outp;
#pragma unroll
    for (int t = 0; t < NWD; ++t)
        op[(size_t)node * (F / 2) + cw + t] = pack2(acc[2 * t], acc[2 * t + 1]);
}

// ---------------- bf16 MFMA GEMM, full-N: C(128x256) = relu(A @ Wt^T + bias) ----------------
// 512 threads = 8 waves (2 m x 4 n), wave tile 64x64 (4x4 frags of 16x16x32)
// MODE 0: C bf16 out.  MODE 1: C fp32 out + fused BN partial sums.

template <int MODE>
__global__ __launch_bounds__(512) void gemm_mfma(
    const u16* __restrict__ A, const u16* __restrict__ Bt, const float* __restrict__ bias,
    void* __restrict__ Cout, float* __restrict__ sums, int M, int K) {
    __shared__ u16 As[128 * 32];
    __shared__ u16 Bs[256 * 32];
    const int tid = threadIdx.x;
    const int w = tid >> 6, lane = tid & 63;
    const int wm = w >> 2, wn = w & 3;
    const int r = lane & 15, rg = lane >> 4;
    const int bm = blockIdx.x * 128;

    floatx4 acc[4][4];
#pragma unroll
    for (int i = 0; i < 4; ++i)
#pragma unroll
        for (int j = 0; j < 4; ++j) acc[i][j] = (floatx4){0.f, 0.f, 0.f, 0.f};

    for (int k0 = 0; k0 < K; k0 += 32) {
        __syncthreads();
        {
            int arow = bm + (tid >> 2);
            if (arow >= M) arow = M - 1;
            load_lds16(A + (size_t)arow * K + k0 + (tid & 3) * 8, As + w * 512);
#pragma unroll
            for (int q = 0; q < 2; ++q) {
                int i = q * 512 + tid;
                int nrow = i >> 2;
                load_lds16(Bt + (size_t)nrow * K + k0 + (i & 3) * 8, Bs + (q * 8 + w) * 512);
            }
        }
        __syncthreads();
        short8 a[4], b[4];
#pragma unroll
        for (int mi = 0; mi < 4; ++mi)
            a[mi] = *(const short8*)(As + (wm * 64 + mi * 16 + r) * 32 + rg * 8);
#pragma unroll
        for (int ni = 0; ni < 4; ++ni)
            b[ni] = *(const short8*)(Bs + (wn * 64 + ni * 16 + r) * 32 + rg * 8);
#pragma unroll
        for (int mi = 0; mi < 4; ++mi)
#pragma unroll
            for (int ni = 0; ni < 4; ++ni)
                acc[mi][ni] = __builtin_amdgcn_mfma_f32_16x16x32_bf16(a[mi], b[ni], acc[mi][ni], 0, 0, 0);
    }

    if (MODE == 0) {
        u16* C = (u16*)Cout;
#pragma unroll
        for (int ni = 0; ni < 4; ++ni) {
            int col = wn * 64 + ni * 16 + r;
            float bv = bias[col];
#pragma unroll
            for (int mi = 0; mi < 4; ++mi)
#pragma unroll
                for (int rr = 0; rr < 4; ++rr) {
                    int row = bm + wm * 64 + mi * 16 + rg * 4 + rr;
                    if (row < M) C[(size_t)row * 256 + col] = f2b(fmaxf(acc[mi][ni][rr] + bv, 0.f));
                }
        }
    } else {
        float* C = (float*)Cout;
#pragma unroll
        for (int ni = 0; ni < 4; ++ni) {
            int col = wn * 64 + ni * 16 + r;
            float bv = bias[col];
            float s = 0.f, s2 = 0.f;
#pragma unroll
            for (int mi = 0; mi < 4; ++mi)
#pragma unroll
                for (int rr = 0; rr < 4; ++rr) {
                    int row = bm + wm * 64 + mi * 16 + rg * 4 + rr;
                    if (row < M) {
                        float v = fmaxf(acc[mi][ni][rr] + bv, 0.f);
                        C[(size_t)row * 256 + col] = v;
                        s += v;
                        s2 += v * v;
                    }
                }
            s += __shfl_xor(s, 16);
            s += __shfl_xor(s, 32);
            s2 += __shfl_xor(s2, 16);
            s2 += __shfl_xor(s2, 32);
            if (rg == 0) {
                atomicAdd(&sums[col], s);
                atomicAdd(&sums[256 + col], s2);
            }
        }
    }
}

// ---------------- BN finalize+apply + bf16 re-pack + fused per-graph pooling ----------------

template <int WRITE_H>
__global__ void bn_apply_pool(const float* __restrict__ Mfp, const float* __restrict__ sums,
                              const float* __restrict__ g, const float* __restrict__ bb,
                              const int* __restrict__ batch, float* __restrict__ out_nodes,
                              u16* __restrict__ H, float* __restrict__ pooled,
                              int col_off, int n, float inv_n) {
    int w = threadIdx.x >> 6, lane = threadIdx.x & 63;
    int base = blockIdx.x * 64 + w * 16;
    if (base >= n) return;
    int c4 = lane << 2;
    float4 s1 = *(const float4*)(sums + c4);
    float4 s2 = *(const float4*)(sums + 256 + c4);
    float4 g4 = *(const float4*)(g + c4);
    float4 b4 = *(const float4*)(bb + c4);
    float4 sc, sh;
    {
        float mux = s1.x * inv_n, muy = s1.y * inv_n, muz = s1.z * inv_n, muw = s1.w * inv_n;
        sc.x = g4.x / sqrtf(s2.x * inv_n - mux * mux + BN_EPS);
        sc.y = g4.y / sqrtf(s2.y * inv_n - muy * muy + BN_EPS);
        sc.z = g4.z / sqrtf(s2.z * inv_n - muz * muz + BN_EPS);
        sc.w = g4.w / sqrtf(s2.w * inv_n - muw * muw + BN_EPS);
        sh.x = b4.x - mux * sc.x;
        sh.y = b4.y - muy * sc.y;
        sh.z = b4.z - muz * sc.z;
        sh.w = b4.w - muw * sc.w;
    }
    float4 acc = make_float4(0.f, 0.f, 0.f, 0.f);
    int gcur = -1;
    int end = min(base + 16, n);
    for (int row = base; row < end; ++row) {
        float4 v = *(const float4*)(Mfp + (size_t)row * 256 + c4);
        float4 o;
        o.x = fmaf(v.x, sc.x, sh.x);
        o.y = fmaf(v.y, sc.y, sh.y);
        o.z = fmaf(v.z, sc.z, sh.z);
        o.w = fmaf(v.w, sc.w, sh.w);
        *(float4*)(out_nodes + (size_t)row * 768 + col_off + c4) = o;
        if (WRITE_H) {
            uint2 pk;
            pk.x = pack2(o.x, o.y);
            pk.y = pack2(o.z, o.w);
            *(uint2*)(H + (size_t)row * 256 + c4) = pk;
        }
        int gg = batch[row];
        if (gg != gcur) {
            if (gcur >= 0) {
                float* pp = pooled + (size_t)gcur * 768 + col_off + c4;
                atomicAdd(pp + 0, acc.x);
                atomicAdd(pp + 1, acc.y);
                atomicAdd(pp + 2, acc.z);
                atomicAdd(pp + 3, acc.w);
            }
            gcur = gg;
            acc = o;
        } else {
            acc.x += o.x; acc.y += o.y; acc.z += o.z; acc.w += o.w;
        }
    }
    if (gcur >= 0) {
        float* pp = pooled + (size_t)gcur * 768 + col_off + c4;
        atomicAdd(pp + 0, acc.x);
        atomicAdd(pp + 1, acc.y);
        atomicAdd(pp + 2, acc.z);
        atomicAdd(pp + 3, acc.w);
    }
}

// ---------------- launch ----------------

extern "C" void kernel_launch(void* const* d_in, const int* in_sizes, int n_in,
                              void* d_out, int out_size, void* d_ws, size_t ws_size,
                              hipStream_t stream) {
    const float* x = (const float*)d_in[0];
    const int* esrc = (const int*)d_in[1];
    const int* edst = esrc + N_EDGES;
    const int* batch = (const int*)d_in[2];

    const float* w1[3] = {(const float*)d_in[3], (const float*)d_in[9], (const float*)d_in[15]};
    const float* b1[3] = {(const float*)d_in[4], (const float*)d_in[10], (const float*)d_in[16]};
    const float* w2[3] = {(const float*)d_in[5], (const float*)d_in[11], (const float*)d_in[17]};
    const float* b2[3] = {(const float*)d_in[6], (const float*)d_in[12], (const float*)d_in[18]};
    const float* bng[3] = {(const float*)d_in[7], (const float*)d_in[13], (const float*)d_in[19]};
    const float* bnb[3] = {(const float*)d_in[8], (const float*)d_in[14], (const float*)d_in[20]};

    float* out_pooled = (float*)d_out;
    float* out_nodes = (float*)d_out + (size_t)N_GRAPHS * 768;

    char* p = (char*)d_ws;
    float* Mfp = (float*)p;            // 50000*256 fp32 (GEMM2 out)
    u16* Abf = (u16*)p;                // aliases Mfp (disjoint in time)
    p += (size_t)N_NODES * 256 * 4;
    u16* T = (u16*)p;  p += (size_t)N_NODES * 256 * 2;   // GEMM1 out
    u16* H = (u16*)p;  p += (size_t)N_NODES * 256 * 2;   // bf16 node feats
    u16* Wall = (u16*)p; p += (size_t)360448 * 2;        // all transposed weights
    // zero region: [sums x3 | deg]  (one memset)
    float* sums = (float*)p; p += 3 * 512 * 4;
    int* deg = (int*)p;      p += (size_t)N_NODES * 4;
    const size_t zero_bytes = 3 * 512 * 4 + (size_t)N_NODES * 4;
    int* row_start = (int*)p; p += (size_t)(N_NODES + 1) * 4;
    int* cursor = (int*)p;    p += (size_t)(N_NODES + 1) * 4;
    int* srcs = (int*)p;      p += (size_t)N_EDGES * 4;
    int* bsum = (int*)p;      p += 256 * 4;
    int* boff = (int*)p;      p += 256 * 4;

    const u16* W1t[3] = {Wall, Wall + 32768, Wall + 98304};
    const u16* W2t[3] = {Wall + 163840, Wall + 229376, Wall + 294912};

    const int NBLK = (N_NODES + 255) / 256;  // 196

    hipMemsetAsync(sums, 0, zero_bytes, stream);
    hipMemsetAsync(out_pooled, 0, (size_t)N_GRAPHS * 768 * sizeof(float), stream);

    // CSR build
    count_deg<<<(N_EDGES + 255) / 256, 256, 0, stream>>>(edst, deg, N_EDGES);
    scan_block<<<NBLK, 256, 0, stream>>>(deg, row_start, bsum, N_NODES);
    scan_partials<<<1, 256, 0, stream>>>(bsum, boff, row_start, cursor, NBLK);
    add_offsets<<<NBLK, 256, 0, stream>>>(row_start, cursor, boff, N_NODES);
    fill_csr<<<(N_EDGES + 255) / 256, 256, 0, stream>>>(esrc, edst, cursor, srcs, N_EDGES);

    // all dtype converts in one kernel
    {
        const int n4 = N_NODES * F_IN / 4;  // 1,600,000 float4s
        const int tot = n4 + 360448;
        convert_all<<<(tot + 255) / 256, 256, 0, stream>>>(
            (const float4*)x, (uint2*)H, n4,
            w1[0], w1[1], w1[2], w2[0], w2[1], w2[2], Wall);
    }

    const int GGRID = (N_NODES + 127) / 128;  // 391
    const int PBLK = (N_NODES + 63) / 64;     // 782
    for (int L = 0; L < 3; ++L) {
        int K1 = (L == 0) ? F_IN : DIM;
        float* sumsL = sums + L * 512;
        if (L == 0)
            aggregate_bf16<128><<<(N_NODES + 3) / 4, 256, 0, stream>>>(H, row_start, srcs, Abf, N_NODES);
        else
            aggregate_bf16<256><<<(N_NODES + 3) / 4, 256, 0, stream>>>(H, row_start, srcs, Abf, N_NODES);
        gemm_mfma<0><<<GGRID, 512, 0, stream>>>(Abf, W1t[L], b1[L], (void*)T, nullptr, N_NODES, K1);
        gemm_mfma<1><<<GGRID, 512, 0, stream>>>(T, W2t[L], b2[L], (void*)Mfp, sumsL, N_NODES, DIM);
        if (L < 2)
            bn_apply_pool<1><<<PBLK, 256, 0, stream>>>(Mfp, sumsL, bng[L], bnb[L], batch,
                                                       out_nodes, H, out_pooled, L * 256, N_NODES, 1.0f / N_NODES);
        else
            bn_apply_pool<0><<<PBLK, 256, 0, stream>>>(Mfp, sumsL, bng[L], bnb[L], batch,
                                                       out_nodes, H, out_pooled, L * 256, N_NODES, 1.0f / N_NODES);
    }
}